// Round 3
// baseline (145.335 us; speedup 1.0000x reference)
//
#include <hip/hip_runtime.h>
#include <math.h>

#define HDIM 128

// ---------------------------------------------------------------------------
// segment_ids is sorted: starts[s] = first t with seg[t] >= s.
// Boundary thread t (seg[t-1] != seg[t]) fills starts for the covered range.
// Thread T-1 fills trailing empty segments with T; thread 0 zeroes the loss
// (stream-ordered before the fused kernel's atomicAdds).
// ---------------------------------------------------------------------------
__global__ __launch_bounds__(256) void seg_bounds_kernel(
    const int* __restrict__ seg, int* __restrict__ starts,
    int Tval, int Bval, float* __restrict__ out) {
    int t = blockIdx.x * blockDim.x + threadIdx.x;
    if (t >= Tval) return;
    int b = seg[t];
    int a = (t == 0) ? -1 : seg[t - 1];
    for (int s = a + 1; s <= b; ++s) starts[s] = t;
    if (t == Tval - 1) {
        for (int s = b + 1; s <= Bval; ++s) starts[s] = Tval;
    }
    if (t == 0) out[0] = 0.0f;
}

// ---------------------------------------------------------------------------
// Fused gather + segment-mean + MLP head + BCE loss. One block = 2 segments.
//
// Phase 1 (gather): 2 waves per segment (parity-split token streams, stride-4
// per half-wave, float4/lane = 2 rows per wave-instr, 4-deep unroll with
// software-pipelined token-id prefetch). Parity partials combine via LDS;
// the scaled segment means land in s_lds[2][128] and never touch global.
//
// Phase 2 (MLP): lane owns (col = wave*32 + lane&31, seg = lane>>5).
// hid_col = tanh(sum_k s_lds[seg][k] * Wh[k][col] + bh[col]); Wh read straight
// from global (64 KB, L2-hot; both halves of a wave hit the same 128 B line).
// p = sigmoid(sum hid*Wo + bo) via half-wave shfl reduce + LDS combine.
// One atomicAdd per block into the pre-zeroed scalar loss.
// ---------------------------------------------------------------------------
__global__ __launch_bounds__(256) void fused_gather_mlp_kernel(
    const int* __restrict__ tok, const float* __restrict__ emb,
    const int* __restrict__ starts, const float* __restrict__ Wh,
    const float* __restrict__ bh, const float* __restrict__ Wo,
    const float* __restrict__ bo, const float* __restrict__ y,
    float* __restrict__ out, int Bval) {
    __shared__ float4 part[2][32];                 // parity-1 gather partials
    __shared__ __align__(16) float s_lds[2][HDIM]; // scaled segment means
    __shared__ float part2[4][2];                  // per-wave loss partials

    int wave = threadIdx.x >> 6;
    int lane = threadIdx.x & 63;
    int segslot = wave >> 1;         // 0..1: which segment of this block
    int parity  = wave & 1;          // 0..1: which token-parity stream
    int s0 = blockIdx.x * 2;
    int s = s0 + segslot;
    int sc = (s < Bval) ? s : (Bval - 1);   // clamp for safe loads

    int t0 = starts[sc];
    int t1 = starts[sc + 1];
    int cnt = t1 - t0;

    int half = lane >> 5;
    int col  = lane & 31;            // float4 column within the 128-f row
    int q = parity * 2 + half;       // stream id 0..3, stride 4 over tokens

    float4 acc = make_float4(0.f, 0.f, 0.f, 0.f);

    int i = t0 + q;
    if (i + 12 < t1) {
        int ta = tok[i], tb = tok[i + 4], tc = tok[i + 8], td = tok[i + 12];
        for (;;) {
            float4 fa = ((const float4*)(emb + (size_t)ta * HDIM))[col];
            float4 fb = ((const float4*)(emb + (size_t)tb * HDIM))[col];
            float4 fc = ((const float4*)(emb + (size_t)tc * HDIM))[col];
            float4 fd = ((const float4*)(emb + (size_t)td * HDIM))[col];
            int ni = i + 16;
            bool more = (ni + 12 < t1);
            if (more) {   // prefetch next ids before the rows' vmcnt wait
                ta = tok[ni]; tb = tok[ni + 4]; tc = tok[ni + 8]; td = tok[ni + 12];
            }
            acc.x += fa.x + fb.x + fc.x + fd.x;
            acc.y += fa.y + fb.y + fc.y + fd.y;
            acc.z += fa.z + fb.z + fc.z + fd.z;
            acc.w += fa.w + fb.w + fc.w + fd.w;
            i = ni;
            if (!more) break;
        }
    }
    for (; i < t1; i += 4) {         // tail: one token per stream step
        int tt = tok[i];
        float4 f = ((const float4*)(emb + (size_t)tt * HDIM))[col];
        acc.x += f.x; acc.y += f.y; acc.z += f.z; acc.w += f.w;
    }

    // combine the two half-waves of this wave
    acc.x += __shfl_xor(acc.x, 32);
    acc.y += __shfl_xor(acc.y, 32);
    acc.z += __shfl_xor(acc.z, 32);
    acc.w += __shfl_xor(acc.w, 32);

    if (parity == 1 && half == 0) part[segslot][col] = acc;
    __syncthreads();
    if (parity == 0 && half == 0) {
        float4 o = part[segslot][col];
        float inv = 1.0f / (float)(cnt > 0 ? cnt : 1);
        float4 m;
        m.x = (acc.x + o.x) * inv;
        m.y = (acc.y + o.y) * inv;
        m.z = (acc.z + o.z) * inv;
        m.w = (acc.w + o.w) * inv;
        ((float4*)s_lds[segslot])[col] = m;
    }
    __syncthreads();

    // ---- Phase 2: MLP + loss, entirely within the block ----
    int mcol = wave * 32 + (lane & 31);   // output column 0..127
    int mseg = lane >> 5;                 // segment slot 0..1
    const float* sv = s_lds[mseg];

    float a = bh[mcol];
    #pragma unroll 8
    for (int k = 0; k < HDIM; ++k) {
        a = fmaf(sv[k], Wh[k * HDIM + mcol], a);
    }
    float h = tanhf(a);
    float pc = h * Wo[mcol];
    // reduce over the 32 lanes of this half-wave (same seg)
    pc += __shfl_xor(pc, 1);
    pc += __shfl_xor(pc, 2);
    pc += __shfl_xor(pc, 4);
    pc += __shfl_xor(pc, 8);
    pc += __shfl_xor(pc, 16);
    if ((lane & 31) == 0) part2[wave][mseg] = pc;
    __syncthreads();

    if (threadIdx.x == 0) {
        float bov = bo[0];
        float lsum = 0.0f;
        for (int g = 0; g < 2; ++g) {
            if (s0 + g < Bval) {
                float z = part2[0][g] + part2[1][g] + part2[2][g] + part2[3][g] + bov;
                float p = 1.0f / (1.0f + expf(-z));
                float lp  = fmaxf(logf(p),    -100.0f);
                float l1p = fmaxf(log1pf(-p), -100.0f);
                float yv = y[s0 + g];
                lsum -= yv * lp + (1.0f - yv) * l1p;
            }
        }
        atomicAdd(out, lsum);
    }
}

// ---------------------------------------------------------------------------
extern "C" void kernel_launch(void* const* d_in, const int* in_sizes, int n_in,
                              void* d_out, int out_size, void* d_ws, size_t ws_size,
                              hipStream_t stream) {
    const int*   tok = (const int*)d_in[0];
    const int*   seg = (const int*)d_in[1];
    const float* y   = (const float*)d_in[2];
    const float* emb = (const float*)d_in[3];
    const float* Wh  = (const float*)d_in[4];
    const float* bh  = (const float*)d_in[5];
    const float* Wo  = (const float*)d_in[6];
    const float* bo  = (const float*)d_in[7];

    int T_ = in_sizes[0];
    int B_ = in_sizes[2];

    float* out = (float*)d_out;

    // ws layout: starts[B+1] ints only (sent round-trip eliminated).
    int* starts = (int*)d_ws;

    seg_bounds_kernel<<<(T_ + 255) / 256, 256, 0, stream>>>(seg, starts, T_, B_, out);
    fused_gather_mlp_kernel<<<(B_ + 1) / 2, 256, 0, stream>>>(
        tok, emb, starts, Wh, bh, Wo, bo, y, out, B_);
}